// Round 1
// baseline (53.477 us; speedup 1.0000x reference)
//
#include <hip/hip_runtime.h>

// GraphUpSamplingLayer: 3-D k=1 NN argmin + batched feature gather.
// B=4, C=512, M=2048 (coarse points), N=8192 (dense points), D=3.
constexpr int B = 4;
constexpr int C = 512;
constexpr int M = 2048;
constexpr int N = 8192;

// ---------------------------------------------------------------------------
// Phase 1: idx[b][n] = argmin_m ||pos[b][n] - sub_pos[b][m]||^2
// f64 difference-form distance => within ~1e-16 of exact math, so the argmin
// is the true argmin (matches the np reference; first-index tie-break kept).
// Block = 256 threads = 64 queries x 4 parts. Part p scans m = 4i+p so the
// wave's 4 distinct LDS float4 reads span 16 banks (conflict-free broadcast).
// ---------------------------------------------------------------------------
__global__ __launch_bounds__(256) void nn_argmin_kernel(
    const float* __restrict__ pos,      // [B][N][3]
    const float* __restrict__ sub_pos,  // [B][M][3]
    int* __restrict__ idx_out)          // [B][N]
{
    __shared__ float4 sp[M];            // 32 KB: (x,y,z,pad)

    const int b  = blockIdx.x >> 7;     // N/64 = 128 blocks per batch
    const int n0 = (blockIdx.x & 127) << 6;
    const int t  = threadIdx.x;

    const float* spb = sub_pos + (size_t)b * (M * 3);
    for (int i = t; i < M; i += 256) {
        sp[i] = make_float4(spb[i * 3 + 0], spb[i * 3 + 1], spb[i * 3 + 2], 0.f);
    }
    __syncthreads();

    const int q = t >> 2, part = t & 3;
    const int n = n0 + q;
    const float* p = pos + ((size_t)b * N + n) * 3;
    const double px = (double)p[0], py = (double)p[1], pz = (double)p[2];

    double best = 1.0e300;
    int bidx = M;  // larger than any real index; overwritten on first iter
    #pragma unroll 4
    for (int i = 0; i < M / 4; ++i) {
        const int m = (i << 2) + part;
        const float4 s = sp[m];
        const double dx = px - (double)s.x;
        const double dy = py - (double)s.y;
        const double dz = pz - (double)s.z;
        const double d = dx * dx + dy * dy + dz * dz;
        if (d < best) { best = d; bidx = m; }  // strict < keeps first index
    }

    // argmin-reduce across the 4 parts (lanes 4q .. 4q+3); on exact ties the
    // smaller global index wins (matches jnp.argmin first-occurrence).
    #pragma unroll
    for (int off = 1; off < 4; off <<= 1) {
        const double ob = __shfl_xor(best, off, 64);
        const int    oi = __shfl_xor(bidx, off, 64);
        if (ob < best || (ob == best && oi < bidx)) { best = ob; bidx = oi; }
    }
    if (part == 0) idx_out[(size_t)b * N + n] = bidx;
}

// ---------------------------------------------------------------------------
// Phase 2: out[b][c][n] = sub_x[b][c][idx[b][n]]
// One block per (b,c): stage the 8 KB row in LDS (random 4x-reused gather),
// stream idx coalesced (int4, L2-resident), write float4-coalesced.
// ---------------------------------------------------------------------------
__global__ __launch_bounds__(256) void gather_kernel(
    const float* __restrict__ sub_x,  // [B][C][M]
    const int* __restrict__ idx,      // [B][N]
    float* __restrict__ out)          // [B][C][N]
{
    __shared__ float row[M];          // 8 KB

    const int b = blockIdx.x >> 9;    // C = 512
    const int c = blockIdx.x & 511;
    const int t = threadIdx.x;

    const float* rsrc = sub_x + ((size_t)b * C + c) * M;
    for (int i = t; i < M; i += 256) row[i] = rsrc[i];
    __syncthreads();

    const int4* iv = (const int4*)(idx + (size_t)b * N);
    float4* ov = (float4*)(out + ((size_t)b * C + c) * N);
    #pragma unroll
    for (int i = t; i < N / 4; i += 256) {
        const int4 ii = iv[i];
        float4 v;
        v.x = row[ii.x];
        v.y = row[ii.y];
        v.z = row[ii.z];
        v.w = row[ii.w];
        ov[i] = v;
    }
}

extern "C" void kernel_launch(void* const* d_in, const int* in_sizes, int n_in,
                              void* d_out, int out_size, void* d_ws, size_t ws_size,
                              hipStream_t stream) {
    const float* sub_x   = (const float*)d_in[0];  // [B][C][M]
    const float* sub_pos = (const float*)d_in[1];  // [B][M][3]
    const float* pos     = (const float*)d_in[2];  // [B][N][3]
    float* out = (float*)d_out;                    // [B][C][N]
    int* idx = (int*)d_ws;                         // B*N*4 = 128 KB scratch

    nn_argmin_kernel<<<B * (N / 64), 256, 0, stream>>>(pos, sub_pos, idx);
    gather_kernel<<<B * C, 256, 0, stream>>>(sub_x, idx, out);
}

// Round 2
// 39.515 us; speedup vs baseline: 1.3533x; 1.3533x over previous
//
#include <hip/hip_runtime.h>

// GraphUpSamplingLayer: 3-D k=1 NN argmin + batched feature gather.
// B=4, C=512, M=2048 (coarse points), N=8192 (dense points), D=3.
constexpr int B = 4;
constexpr int C = 512;
constexpr int M = 2048;
constexpr int N = 8192;

// ---------------------------------------------------------------------------
// Phase 1: idx[b][n] = argmin_m ||pos[b][n] - sub_pos[b][m]||^2
//
// f32 difference-form distance. R1 established the exact argmin == np ref
// argmin (absmax 0.0 with f64), i.e. min-gaps exceed the f32 expanded-form
// noise the np reference itself carries (~1e-6). Difference-form f32 noise
// is ~5x smaller (~2e-7 rel), so the argmin is preserved.
//
// Layout: 256 threads/block. P=16 lanes per query (candidate-interleaved),
// Q=4 queries per thread -> one LDS float4 read feeds 4 query-pairs
// (LDS traffic 4 B/pair, ~4 us total). 64 queries/block -> 512 blocks
// = 8 waves/CU. Loop: M/16 = 128 iters.
// ---------------------------------------------------------------------------
__global__ __launch_bounds__(256) void nn_argmin_kernel(
    const float* __restrict__ pos,      // [B][N][3]
    const float* __restrict__ sub_pos,  // [B][M][3]
    int* __restrict__ idx_out)          // [B][N]
{
    __shared__ float4 sp[M];            // 32 KB: (x,y,z,pad)

    const int b  = blockIdx.x >> 7;     // 128 blocks per batch
    const int n0 = (blockIdx.x & 127) << 6;  // 64 queries per block
    const int t  = threadIdx.x;

    const float* spb = sub_pos + (size_t)b * (M * 3);
    #pragma unroll
    for (int i = t; i < M; i += 256) {
        sp[i] = make_float4(spb[i * 3 + 0], spb[i * 3 + 1], spb[i * 3 + 2], 0.f);
    }
    __syncthreads();

    const int part = t & 15;            // which candidate slice
    const int g    = t >> 4;            // query group (16 per block)
    const int nbase = n0 + g * 4;       // this thread's 4 queries

    float px[4], py[4], pz[4], best[4];
    int bidx[4];
    #pragma unroll
    for (int q = 0; q < 4; ++q) {
        const float* pp = pos + ((size_t)b * N + nbase + q) * 3;
        px[q] = pp[0]; py[q] = pp[1]; pz[q] = pp[2];
        best[q] = 1e30f;
        bidx[q] = M;
    }

    #pragma unroll 4
    for (int i = 0; i < M / 16; ++i) {
        const int m = (i << 4) + part;
        const float4 s = sp[m];
        #pragma unroll
        for (int q = 0; q < 4; ++q) {
            const float dx = px[q] - s.x;
            const float dy = py[q] - s.y;
            const float dz = pz[q] - s.z;
            const float d = dx * dx + dy * dy + dz * dz;
            if (d < best[q]) { best[q] = d; bidx[q] = m; }  // strict <: first idx
        }
    }

    // argmin-reduce across the 16 parts; exact ties -> smaller global index
    // (jnp.argmin first-occurrence semantics).
    #pragma unroll
    for (int off = 1; off < 16; off <<= 1) {
        #pragma unroll
        for (int q = 0; q < 4; ++q) {
            const float ob = __shfl_xor(best[q], off, 64);
            const int   oi = __shfl_xor(bidx[q], off, 64);
            if (ob < best[q] || (ob == best[q] && oi < bidx[q])) {
                best[q] = ob; bidx[q] = oi;
            }
        }
    }
    if (part == 0) {
        #pragma unroll
        for (int q = 0; q < 4; ++q)
            idx_out[(size_t)b * N + nbase + q] = bidx[q];
    }
}

// ---------------------------------------------------------------------------
// Phase 2: out[b][c][n] = sub_x[b][c][idx[b][n]]
// HBM-roofline bound (64 MB write + 16 MB read ~= 12.7 us floor); unchanged.
// ---------------------------------------------------------------------------
__global__ __launch_bounds__(256) void gather_kernel(
    const float* __restrict__ sub_x,  // [B][C][M]
    const int* __restrict__ idx,      // [B][N]
    float* __restrict__ out)          // [B][C][N]
{
    __shared__ float row[M];          // 8 KB

    const int b = blockIdx.x >> 9;    // C = 512
    const int c = blockIdx.x & 511;
    const int t = threadIdx.x;

    const float* rsrc = sub_x + ((size_t)b * C + c) * M;
    for (int i = t; i < M; i += 256) row[i] = rsrc[i];
    __syncthreads();

    const int4* iv = (const int4*)(idx + (size_t)b * N);
    float4* ov = (float4*)(out + ((size_t)b * C + c) * N);
    #pragma unroll
    for (int i = t; i < N / 4; i += 256) {
        const int4 ii = iv[i];
        float4 v;
        v.x = row[ii.x];
        v.y = row[ii.y];
        v.z = row[ii.z];
        v.w = row[ii.w];
        ov[i] = v;
    }
}

extern "C" void kernel_launch(void* const* d_in, const int* in_sizes, int n_in,
                              void* d_out, int out_size, void* d_ws, size_t ws_size,
                              hipStream_t stream) {
    const float* sub_x   = (const float*)d_in[0];  // [B][C][M]
    const float* sub_pos = (const float*)d_in[1];  // [B][M][3]
    const float* pos     = (const float*)d_in[2];  // [B][N][3]
    float* out = (float*)d_out;                    // [B][C][N]
    int* idx = (int*)d_ws;                         // B*N*4 = 128 KB scratch

    nn_argmin_kernel<<<B * (N / 64), 256, 0, stream>>>(pos, sub_pos, idx);
    gather_kernel<<<B * C, 256, 0, stream>>>(sub_x, idx, out);
}